// Round 11
// baseline (645.627 us; speedup 1.0000x reference)
//
#include <hip/hip_runtime.h>
#include <math.h>

// Problem constants (from reference): T=4096, IN=512, K=64, V=64, H=4096
#define T_DIM 4096
#define IN_DIM 512
#define K_DIM 64
#define V_DIM 64
#define H_DIM 4096
#define CHUNKS 256
#define CLEN 16   // T_DIM / CHUNKS

typedef __attribute__((ext_vector_type(8))) short short8;           // 8 bf16 = 4 VGPRs
typedef __attribute__((ext_vector_type(4))) float f32x4;

// ---------------- activations ----------------
__device__ __forceinline__ float phi_act(float v){
    return v > 0.f ? (v + 1.f) : (expm1f(v) + 1.f);
}
// mish(x) = x*tanh(softplus(x)) = x*(1 - 2/(u*(u+2)+2)), u=e^x  (exact identity).
// Branch-free; limits: x->+inf -> x (2/inf=0), x->-inf -> x*e^x -> 0.
// Validated on-hardware round 10 (absmax pass; cut GEMM2 VALUBusy 51%->17%).
__device__ __forceinline__ float mish_act(float v){
    const float u = __expf(v);
    const float w = u * (u + 2.f);
    return v * (1.f - 2.f / (w + 2.f));
}
// fp32 -> bf16 round-to-nearest-even (bit trick)
__device__ __forceinline__ unsigned short f2bf(float f){
    union { float f; unsigned int u; } x; x.f = f;
    unsigned int u = x.u + 0x7fffu + ((x.u >> 16) & 1u);
    return (unsigned short)(u >> 16);
}

// async 16B global->LDS (dest = wave-uniform base + lane*16; layout must be contiguous per lane)
__device__ __forceinline__ void async16(const unsigned short* g, unsigned short* l){
    __builtin_amdgcn_global_load_lds(
        (const __attribute__((address_space(1))) unsigned int*)g,
        (__attribute__((address_space(3))) unsigned int*)l,
        16, 0, 0);
}

// inline-asm ds_read_b128 with compile-time immediate offset. Opaque to the
// compiler's waitcnt insertion -> we control lgkmcnt/vmcnt entirely; offset:imm
// keeps address VALU at zero inside the K-loop.
__device__ __forceinline__ short8 dsr128o(unsigned addr, int off){
    short8 d;
    asm volatile("ds_read_b128 %0, %1 offset:%2" : "=v"(d) : "v"(addr), "i"(off));
    return d;
}

#define LGKM(n)  asm volatile("s_waitcnt lgkmcnt(" #n ")" ::: "memory")
#define VMCNT(n) asm volatile("s_waitcnt vmcnt(" #n ")" ::: "memory")
#define SB0()    __builtin_amdgcn_sched_barrier(0)

// ---------------- prep kernel: 3 fp32 projections + 5 bf16 conversions, ONE dispatch -----
// blocks 0..191: projection (which = bid>>6): {k=phi(x@Wk^T), q=phi(x@Wq^T), v=x@Wv^T+bv}
// blocks 192.. : grid-stride bf16 conversion over {x, Wskip, W1, W2, W3} (9502720 float4s)
#define CVT_X4   524288          // T*IN/4
#define CVT_WS   524288          // H*IN/4
#define CVT_W1   65536           // H*V/4
#define CVT_W2   4194304         // H*H/4
#define CVT_TOT  9502720
__global__ __launch_bounds__(256) void prep_kernel(
    const float* __restrict__ x,
    const float* __restrict__ Wk, const float* __restrict__ Wq, const float* __restrict__ Wv,
    const float* __restrict__ bv,
    float* __restrict__ kbuf, float* __restrict__ qbuf, float* __restrict__ vbuf,
    const float* __restrict__ Wskip, const float* __restrict__ W1,
    const float* __restrict__ W2, const float* __restrict__ W3,
    unsigned short* __restrict__ xb, unsigned short* __restrict__ Wskipb,
    unsigned short* __restrict__ W1b, unsigned short* __restrict__ W2b,
    unsigned short* __restrict__ W3b)
{
    __shared__ float As[16][68];
    __shared__ float Bs[16][68];
    const int bid = blockIdx.x;
    const int tid = threadIdx.x;

    if (bid < 192){
        // ---- projection path (uniform per block; __syncthreads is block-uniform) ----
        const int which = bid >> 6;
        const float* B0 = which == 0 ? Wk : which == 1 ? Wq : Wv;
        float* Y        = which == 0 ? kbuf : which == 1 ? qbuf : vbuf;
        const int actp  = which < 2;
        const int bm    = (bid & 63) * 64;
        const int lrow  = tid >> 2;
        const int lk4   = (tid & 3) * 4;
        const int tm    = (tid >> 4) * 4;
        const int tn    = (tid & 15) * 4;
        float acc[4][4] = {};
        const float* aptr = x  + (size_t)(bm + lrow) * IN_DIM + lk4;
        const float* bptr = B0 + (size_t)lrow * IN_DIM + lk4;
        for (int k0 = 0; k0 < IN_DIM; k0 += 16){
            const float4 av  = *(const float4*)(aptr + k0);
            const float4 bv4 = *(const float4*)(bptr + k0);
            __syncthreads();
            As[lk4+0][lrow]=av.x;  As[lk4+1][lrow]=av.y;  As[lk4+2][lrow]=av.z;  As[lk4+3][lrow]=av.w;
            Bs[lk4+0][lrow]=bv4.x; Bs[lk4+1][lrow]=bv4.y; Bs[lk4+2][lrow]=bv4.z; Bs[lk4+3][lrow]=bv4.w;
            __syncthreads();
            #pragma unroll
            for (int kk = 0; kk < 16; ++kk){
                const float4 a = *(const float4*)&As[kk][tm];
                const float4 b = *(const float4*)&Bs[kk][tn];
                acc[0][0] += a.x*b.x; acc[0][1] += a.x*b.y; acc[0][2] += a.x*b.z; acc[0][3] += a.x*b.w;
                acc[1][0] += a.y*b.x; acc[1][1] += a.y*b.y; acc[1][2] += a.y*b.z; acc[1][3] += a.y*b.w;
                acc[2][0] += a.z*b.x; acc[2][1] += a.z*b.y; acc[2][2] += a.z*b.z; acc[2][3] += a.z*b.w;
                acc[3][0] += a.w*b.x; acc[3][1] += a.w*b.y; acc[3][2] += a.w*b.z; acc[3][3] += a.w*b.w;
            }
        }
        float badd[4] = {0.f, 0.f, 0.f, 0.f};
        if (which == 2){
            badd[0] = bv[tn+0]; badd[1] = bv[tn+1]; badd[2] = bv[tn+2]; badd[3] = bv[tn+3];
        }
        #pragma unroll
        for (int i = 0; i < 4; ++i){
            float r0 = acc[i][0] + badd[0];
            float r1 = acc[i][1] + badd[1];
            float r2 = acc[i][2] + badd[2];
            float r3 = acc[i][3] + badd[3];
            if (actp){ r0 = phi_act(r0); r1 = phi_act(r1); r2 = phi_act(r2); r3 = phi_act(r3); }
            *(float4*)&Y[(size_t)(bm + tm + i) * 64 + tn] = make_float4(r0, r1, r2, r3);
        }
        return;
    }

    // ---- conversion path: grid-stride over 5 segments ----
    const int nb = gridDim.x - 192;
    for (int i = (bid - 192) * 256 + tid; i < CVT_TOT; i += nb * 256){
        const float* src; unsigned short* dst; int off;
        if      (i < CVT_X4)                          { src = x;     dst = xb;     off = i; }
        else if (i < CVT_X4 + CVT_WS)                 { src = Wskip; dst = Wskipb; off = i - CVT_X4; }
        else if (i < CVT_X4 + CVT_WS + CVT_W1)        { src = W1;    dst = W1b;    off = i - CVT_X4 - CVT_WS; }
        else if (i < CVT_X4 + CVT_WS + CVT_W1 + CVT_W2){ src = W2;   dst = W2b;    off = i - CVT_X4 - CVT_WS - CVT_W1; }
        else                                          { src = W3;    dst = W3b;    off = i - CVT_X4 - CVT_WS - CVT_W1 - CVT_W2; }
        float4 v = ((const float4*)src)[off];
        ushort4 o;
        o.x = f2bf(v.x); o.y = f2bf(v.y); o.z = f2bf(v.z); o.w = f2bf(v.w);
        ((ushort4*)dst)[off] = o;
    }
}

// ---------------- 256x256 wave-pipelined bf16 MFMA GEMM ----------------
// Round-8/10 verified structure; THIS round's single change: the 8 staging loads of
// tile t+1 are SPREAD 4-2-2 across the MFMA clusters (was: one burst at tile start).
// Mechanism: 64 x 1KB load instructions per CU issued in one burst slam the L2 queue
// then leave it idle for the rest of the tile; spreading smooths demand. Race-safety
// identical: staging targets buf (t+1)&1 (never read during tile t); boundary VMCNT(0)
// + s_barrier publishes; lgkm ladder counts only DS ops (global_load_lds is vmcnt-only).
// Last staged pair ages ~2 clusters (~3000 cyc >> 900-cyc HBM latency).
__global__ __launch_bounds__(512, 2) void gemm256p(
    const unsigned short* __restrict__ A0, const unsigned short* __restrict__ B0, int K0,
    const unsigned short* __restrict__ A1, const unsigned short* __restrict__ B1, int K1,
    const float* __restrict__ bias0, const float* __restrict__ bias1,
    void* __restrict__ Y, int N, int act, int out_bf16)
{
    __shared__ unsigned short As[2][16384];   // 2 x 32 KiB
    __shared__ unsigned short Bs[2][16384];   // 2 x 32 KiB
    const int tid  = threadIdx.x;
    const int lane = tid & 63;
    const int w    = tid >> 6;          // wave 0..7
    const int wr   = w >> 2;            // 0..1  (M half)
    const int wc   = w & 3;             // 0..3  (N quarter)
    const int l15  = lane & 15;
    const int quad = lane >> 4;

    // Bijective XCD-aware swizzle for the 16x16 grid: XCD x owns a 4(M) x 8(N) patch.
    int bx = blockIdx.x, by = blockIdx.y;
    if (gridDim.x == 16 && gridDim.y == 16){
        const int id  = by * 16 + bx;       // dispatch-linear (blockIdx.x fastest)
        const int xcd = id & 7;             // default round-robin XCD assignment
        const int loc = id >> 3;            // 0..31 within XCD
        bx = (xcd & 3) * 4 + (loc & 3);
        by = (xcd >> 2) * 8 + (loc >> 2);
    }
    const int bm = bx * 256;
    const int bn = by * 256;

    // staging geometry: thread owns chunk g*512+tid of each 2048-chunk tile (16 B each);
    // row = g*64 + (tid>>3), swizzled k-chunk kc = (tid&7) ^ (row&7).
    const int r0 = tid >> 3;
    const int kc = (tid & 7) ^ (r0 & 7);

    // loop-invariant LDS read bases (buffer 0); frag mi at +mi*2048 B, buffer 1 at +32768 B.
    const unsigned asB = (unsigned)(size_t)&As[0][0];
    const unsigned bsB = (unsigned)(size_t)&Bs[0][0];
    const unsigned bA0 = asB + (unsigned)(((wr * 128 + l15) * 8 + ((0 + quad) ^ (l15 & 7))) * 16);
    const unsigned bA1 = asB + (unsigned)(((wr * 128 + l15) * 8 + ((4 + quad) ^ (l15 & 7))) * 16);
    const unsigned bB0 = bsB + (unsigned)(((wc * 64  + l15) * 8 + ((0 + quad) ^ (l15 & 7))) * 16);
    const unsigned bB1 = bsB + (unsigned)(((wc * 64  + l15) * 8 + ((4 + quad) ^ (l15 & 7))) * 16);

    f32x4 acc[8][4] = {};

    for (int seg = 0; seg < 2; ++seg){
        const unsigned short* A = seg ? A1 : A0;
        const unsigned short* B = seg ? B1 : B0;
        const int Kd = seg ? K1 : K0;
        if (Kd <= 0 || A == nullptr) continue;
        const int NT = Kd / 64;
        const size_t gstride = (size_t)64 * Kd;
        const unsigned short* pA = A + (size_t)bm * Kd + (size_t)r0 * Kd + kc * 8;
        const unsigned short* pB = B + (size_t)bn * Kd + (size_t)r0 * Kd + kc * 8;

        // ---- prologue: stage tile 0 into buf0, drain, publish ----
        #pragma unroll
        for (int g = 0; g < 4; ++g) async16(pA + g * gstride, &As[0][(g * 512 + tid) * 8]);
        #pragma unroll
        for (int g = 0; g < 4; ++g) async16(pB + g * gstride, &Bs[0][(g * 512 + tid) * 8]);
        VMCNT(0);
        __builtin_amdgcn_s_barrier();

        for (int t = 0; t < NT; ++t){
            const unsigned bo = (unsigned)(t & 1) * 32768u;
            const unsigned aA0 = bA0 + bo, aA1 = bA1 + bo, aB0 = bB0 + bo, aB1 = bB1 + bo;
            const bool st = (t + 1 < NT);
            const int  bi = (t + 1) & 1;
            const int  kn = (t + 1) * 64;
            short8 fa0[4], fa1[4], fb0[4], fb1[4];

            // issue fb0 (ops 1-4), fa0 (5-8); stage A g0,g1 + B g0,g1; fa1 (9-12)
            #pragma unroll
            for (int ni = 0; ni < 4; ++ni) fb0[ni] = dsr128o(aB0, ni * 2048);
            #pragma unroll
            for (int mi = 0; mi < 4; ++mi) fa0[mi] = dsr128o(aA0, mi * 2048);
            if (st){
                async16(pA + 0 * gstride + kn, &As[bi][(0 * 512 + tid) * 8]);
                async16(pA + 1 * gstride + kn, &As[bi][(1 * 512 + tid) * 8]);
                async16(pB + 0 * gstride + kn, &Bs[bi][(0 * 512 + tid) * 8]);
                async16(pB + 1 * gstride + kn, &Bs[bi][(1 * 512 + tid) * 8]);
            }
            #pragma unroll
            for (int mi = 0; mi < 4; ++mi) fa1[mi] = dsr128o(aA0, (4 + mi) * 2048);

            // cluster 0: acc[0:4] x fb0 (needs ops 1-8), laddered per mi
            __builtin_amdgcn_s_setprio(1);
            LGKM(7); SB0();
            #pragma unroll
            for (int ni = 0; ni < 4; ++ni)
                acc[0][ni] = __builtin_amdgcn_mfma_f32_16x16x32_bf16(fa0[0], fb0[ni], acc[0][ni], 0, 0, 0);
            LGKM(6); SB0();
            #pragma unroll
            for (int ni = 0; ni < 4; ++ni)
                acc[1][ni] = __builtin_amdgcn_mfma_f32_16x16x32_bf16(fa0[1], fb0[ni], acc[1][ni], 0, 0, 0);
            LGKM(5); SB0();
            #pragma unroll
            for (int ni = 0; ni < 4; ++ni)
                acc[2][ni] = __builtin_amdgcn_mfma_f32_16x16x32_bf16(fa0[2], fb0[ni], acc[2][ni], 0, 0, 0);
            LGKM(4); SB0();
            #pragma unroll
            for (int ni = 0; ni < 4; ++ni)
                acc[3][ni] = __builtin_amdgcn_mfma_f32_16x16x32_bf16(fa0[3], fb0[ni], acc[3][ni], 0, 0, 0);
            __builtin_amdgcn_s_setprio(0);

            // stage A g2 + B g2 (spread); then issue fb1 (13-16), fa0' (17-20)
            if (st){
                async16(pA + 2 * gstride + kn, &As[bi][(2 * 512 + tid) * 8]);
                async16(pB + 2 * gstride + kn, &Bs[bi][(2 * 512 + tid) * 8]);
            }
            #pragma unroll
            for (int ni = 0; ni < 4; ++ni) fb1[ni] = dsr128o(aB1, ni * 2048);
            #pragma unroll
            for (int mi = 0; mi < 4; ++mi) fa0[mi] = dsr128o(aA1, mi * 2048);

            // cluster 1: acc[4:8] x fb0 (needs fa1 = ops 9-12), laddered
            __builtin_amdgcn_s_setprio(1);
            LGKM(11); SB0();
            #pragma unroll
            for (int ni = 0; ni < 4; ++ni)
                acc[4][ni] = __builtin_amdgcn_mfma_f32_16x16x32_bf16(fa1[0], fb0[ni], acc[4][ni], 0, 0, 0);
            LGKM(10); SB0();
            #pragma unroll
            for (int ni = 0; ni < 4; ++ni)
                acc[5][ni] = __builtin_amdgcn_mfma_f32_16x16x32_bf16(fa1[1], fb0[ni], acc[5][ni], 0, 0, 0);
            LGKM(9); SB0();
            #pragma unroll
            for (int ni = 0; ni < 4; ++ni)
                acc[6][ni] = __builtin_amdgcn_mfma_f32_16x16x32_bf16(fa1[2], fb0[ni], acc[6][ni], 0, 0, 0);
            LGKM(8); SB0();
            #pragma unroll
            for (int ni = 0; ni < 4; ++ni)
                acc[7][ni] = __builtin_amdgcn_mfma_f32_16x16x32_bf16(fa1[3], fb0[ni], acc[7][ni], 0, 0, 0);
            __builtin_amdgcn_s_setprio(0);

            // stage A g3 + B g3 (spread, last pair; ages clusters 2+3); issue fa1' (21-24)
            if (st){
                async16(pA + 3 * gstride + kn, &As[bi][(3 * 512 + tid) * 8]);
                async16(pB + 3 * gstride + kn, &Bs[bi][(3 * 512 + tid) * 8]);
            }
            #pragma unroll
            for (int mi = 0; mi < 4; ++mi) fa1[mi] = dsr128o(aA1, (4 + mi) * 2048);

            // cluster 2: acc[0:4] x fb1 (needs ops 13-20), laddered
            __builtin_amdgcn_s_setprio(1);
            LGKM(7); SB0();
            #pragma unroll
            for (int ni = 0; ni < 4; ++ni)
                acc[0][ni] = __builtin_amdgcn_mfma_f32_16x16x32_bf16(fa0[0], fb1[ni], acc[0][ni], 0, 0, 0);
            LGKM(6); SB0();
            #pragma unroll
            for (int ni = 0; ni < 4; ++ni)
                acc[1][ni] = __builtin_amdgcn_mfma_f32_16x16x32_bf16(fa0[1], fb1[ni], acc[1][ni], 0, 0, 0);
            LGKM(5); SB0();
            #pragma unroll
            for (int ni = 0; ni < 4; ++ni)
                acc[2][ni] = __builtin_amdgcn_mfma_f32_16x16x32_bf16(fa0[2], fb1[ni], acc[2][ni], 0, 0, 0);
            LGKM(4); SB0();
            #pragma unroll
            for (int ni = 0; ni < 4; ++ni)
                acc[3][ni] = __builtin_amdgcn_mfma_f32_16x16x32_bf16(fa0[3], fb1[ni], acc[3][ni], 0, 0, 0);

            // cluster 3: acc[4:8] x fb1 (needs ops 21-24), laddered
            LGKM(3); SB0();
            #pragma unroll
            for (int ni = 0; ni < 4; ++ni)
                acc[4][ni] = __builtin_amdgcn_mfma_f32_16x16x32_bf16(fa1[0], fb1[ni], acc[4][ni], 0, 0, 0);
            LGKM(2); SB0();
            #pragma unroll
            for (int ni = 0; ni < 4; ++ni)
                acc[5][ni] = __builtin_amdgcn_mfma_f32_16x16x32_bf16(fa1[1], fb1[ni], acc[5][ni], 0, 0, 0);
            LGKM(1); SB0();
            #pragma unroll
            for (int ni = 0; ni < 4; ++ni)
                acc[6][ni] = __builtin_amdgcn_mfma_f32_16x16x32_bf16(fa1[2], fb1[ni], acc[6][ni], 0, 0, 0);
            LGKM(0); SB0();
            #pragma unroll
            for (int ni = 0; ni < 4; ++ni)
                acc[7][ni] = __builtin_amdgcn_mfma_f32_16x16x32_bf16(fa1[3], fb1[ni], acc[7][ni], 0, 0, 0);
            __builtin_amdgcn_s_setprio(0);

            // tile boundary: own tile-t+1 loads drained, then publish.
            if (st){
                VMCNT(0);
                __builtin_amdgcn_s_barrier();
            }
        }
        // inter-segment: next prologue's VMCNT(0)+barrier is the rendezvous; buffer
        // written next (buf0) had its reads complete before the last boundary barrier.
    }

    // epilogue (direct stores): C/D mapping col=lane&15, row=quad*4+reg
    #pragma unroll
    for (int ni = 0; ni < 4; ++ni){
        const int col = bn + wc * 64 + ni * 16 + l15;
        float bb = 0.f;
        if (bias0) bb += bias0[col];
        if (bias1) bb += bias1[col];
        #pragma unroll
        for (int mi = 0; mi < 8; ++mi){
            #pragma unroll
            for (int r = 0; r < 4; ++r){
                const int row = bm + wr * 128 + mi * 16 + quad * 4 + r;
                float v = acc[mi][ni][r] + bb;
                if (act == 2) v = mish_act(v);
                if (out_bf16) ((unsigned short*)Y)[(size_t)row * N + col] = f2bf(v);
                else          ((float*)Y)[(size_t)row * N + col] = v;
            }
        }
    }
}

// ---------------- segmented scan, pass A (one-shot LDS chunk load, barrier-free loop) ----
__global__ __launch_bounds__(256) void scan_passA(
    const float* __restrict__ kbuf, const float* __restrict__ vbuf,
    const int* __restrict__ start,
    float* __restrict__ chunkS, float* __restrict__ chunkZ, int* __restrict__ chunkFlag)
{
    const int c   = blockIdx.x;
    const int tid = threadIdx.x;
    const int j   = tid >> 2;
    const int i0  = (tid & 3) * 16;
    __shared__ float k_lds[CLEN][64], v_lds[CLEN][64];
    __shared__ int   st_lds[CLEN];
    // one-shot chunk load: 16 rows x 64 floats = 256 float4 (coalesced)
    ((float4*)&k_lds[0][0])[tid] = ((const float4*)(kbuf + (size_t)c * CLEN * K_DIM))[tid];
    ((float4*)&v_lds[0][0])[tid] = ((const float4*)(vbuf + (size_t)c * CLEN * V_DIM))[tid];
    if (tid < CLEN) st_lds[tid] = start[c * CLEN + tid];
    __syncthreads();

    float s_loc[16];
    #pragma unroll
    for (int e = 0; e < 16; ++e) s_loc[e] = 0.f;
    float z_loc = 0.f;
    int flag = 0;
    for (int tt = 0; tt < CLEN; ++tt){
        if (st_lds[tt]){
            #pragma unroll
            for (int e = 0; e < 16; ++e) s_loc[e] = 0.f;
            z_loc = 0.f;
            flag = 1;
        }
        const float vj = v_lds[tt][j];
        #pragma unroll
        for (int e = 0; e < 16; ++e) s_loc[e] += k_lds[tt][i0 + e] * vj;
        if (tid < 64) z_loc += k_lds[tt][tid];
    }
    #pragma unroll
    for (int e = 0; e < 16; ++e) chunkS[(size_t)c*4096 + (i0 + e)*64 + j] = s_loc[e];
    if (tid < 64) chunkZ[c*64 + tid] = z_loc;
    if (tid == 0) chunkFlag[c] = flag;
}

// ---------------- pass B: exclusive cross-chunk combine (64 blocks x 64 thr) ----------------
__global__ __launch_bounds__(64) void scan_passB(
    const float* __restrict__ chunkS, const float* __restrict__ chunkZ, const int* __restrict__ chunkFlag,
    const float* __restrict__ s0, const float* __restrict__ z0,
    float* __restrict__ carryS, float* __restrict__ carryZ)
{
    const int ij = blockIdx.x * 64 + threadIdx.x;
    float e = s0[ij];
    for (int c = 0; c < CHUNKS; ++c){
        carryS[(size_t)c*4096 + ij] = e;
        const int f   = chunkFlag[c];
        const float s = chunkS[(size_t)c*4096 + ij];
        e = f ? s : (e + s);
    }
    if (ij < 64){
        float ez = z0[ij];
        for (int c = 0; c < CHUNKS; ++c){
            carryZ[c*64 + ij] = ez;
            const int f   = chunkFlag[c];
            const float z = chunkZ[c*64 + ij];
            ez = f ? z : (ez + z);
        }
    }
}

// ---------------- pass C: replay with carry (one-shot LDS chunk load); emit s,z,att ----
__global__ __launch_bounds__(256) void scan_passC(
    const float* __restrict__ kbuf, const float* __restrict__ vbuf, const float* __restrict__ qbuf,
    const int* __restrict__ start,
    const float* __restrict__ carryS, const float* __restrict__ carryZ,
    float* __restrict__ s_out, float* __restrict__ z_out, unsigned short* __restrict__ attout)
{
    const int c   = blockIdx.x;
    const int tid = threadIdx.x;
    const int j   = tid >> 2;
    const int g   = tid & 3;
    const int i0  = g * 16;
    __shared__ float k_lds[CLEN][64], v_lds[CLEN][64], q_lds[CLEN][64];
    __shared__ int   st_lds[CLEN];
    __shared__ float numer_lds[64];
    __shared__ float stage[4096];
    // one-shot chunk load
    ((float4*)&k_lds[0][0])[tid] = ((const float4*)(kbuf + (size_t)c * CLEN * K_DIM))[tid];
    ((float4*)&v_lds[0][0])[tid] = ((const float4*)(vbuf + (size_t)c * CLEN * V_DIM))[tid];
    ((float4*)&q_lds[0][0])[tid] = ((const float4*)(qbuf + (size_t)c * CLEN * K_DIM))[tid];
    if (tid < CLEN) st_lds[tid] = start[c * CLEN + tid];

    float s_loc[16];
    #pragma unroll
    for (int e = 0; e < 16; ++e) s_loc[e] = carryS[(size_t)c*4096 + (i0 + e)*64 + j];
    float z_loc = (tid < 64) ? carryZ[c*64 + tid] : 0.f;
    __syncthreads();

    const int t0 = c * CLEN;
    for (int tt = 0; tt < CLEN; ++tt){
        const int t  = t0 + tt;
        const int st = st_lds[tt];
        if (st){
            #pragma unroll
            for (int e = 0; e < 16; ++e) s_loc[e] = 0.f;
        }
        const float vj = v_lds[tt][j];
        float np = 0.f;
        #pragma unroll
        for (int e = 0; e < 16; ++e){
            s_loc[e] += k_lds[tt][i0 + e] * vj;
            np += s_loc[e] * q_lds[tt][i0 + e];
        }
        np += __shfl_down(np, 1, 64);
        np += __shfl_down(np, 2, 64);
        if (g == 0) numer_lds[j] = np;
        float denom = 1.f;
        if (tid < 64){
            z_loc = (st ? 0.f : z_loc) + k_lds[tt][tid];
            z_out[(size_t)t*K_DIM + tid] = z_loc;
            float zs = z_loc;
            float qs = q_lds[tt][tid];
            #pragma unroll
            for (int o = 32; o > 0; o >>= 1){
                zs += __shfl_down(zs, o, 64);
                qs += __shfl_down(qs, o, 64);
            }
            zs = __shfl(zs, 0, 64);
            qs = __shfl(qs, 0, 64);
            denom = fmaxf(zs * qs, 1e-6f);
        }
        #pragma unroll
        for (int e = 0; e < 16; ++e) stage[(i0 + e)*64 + j] = s_loc[e];
        __syncthreads();
        float4* so = (float4*)(s_out + (size_t)t*4096);
        const float4* stv = (const float4*)stage;
        #pragma unroll
        for (int r = 0; r < 4; ++r) so[tid + 256*r] = stv[tid + 256*r];
        if (tid < 64) attout[(size_t)t*V_DIM + tid] = f2bf(numer_lds[tid] / denom);
        __syncthreads();
    }
}

// ---------------- LayerNorm over H=4096, in place ----------------
__global__ __launch_bounds__(256) void ln_kernel(
    float* __restrict__ h, const float* __restrict__ g, const float* __restrict__ b)
{
    __shared__ float sm[4];
    const int t   = blockIdx.x;
    const int tid = threadIdx.x;
    float* row = h + (size_t)t * H_DIM;
    float4 v[4];
    float s = 0.f;
    #pragma unroll
    for (int r = 0; r < 4; ++r){
        v[r] = ((const float4*)row)[tid + 256*r];
        s += v[r].x + v[r].y + v[r].z + v[r].w;
    }
    #pragma unroll
    for (int o = 32; o > 0; o >>= 1) s += __shfl_down(s, o, 64);
    if ((tid & 63) == 0) sm[tid >> 6] = s;
    __syncthreads();
    const float mu = (sm[0] + sm[1] + sm[2] + sm[3]) * (1.f / H_DIM);
    __syncthreads();
    float sq = 0.f;
    #pragma unroll
    for (int r = 0; r < 4; ++r){
        float dx = v[r].x - mu, dy = v[r].y - mu, dz = v[r].z - mu, dw = v[r].w - mu;
        sq += dx*dx + dy*dy + dz*dz + dw*dw;
    }
    #pragma unroll
    for (int o = 32; o > 0; o >>= 1) sq += __shfl_down(sq, o, 64);
    if ((tid & 63) == 0) sm[tid >> 6] = sq;
    __syncthreads();
    const float var = (sm[0] + sm[1] + sm[2] + sm[3]) * (1.f / H_DIM);
    const float inv = rsqrtf(var + 1e-5f);
    #pragma unroll
    for (int r = 0; r < 4; ++r){
        const int i4 = tid + 256*r;
        const float4 gg = ((const float4*)g)[i4];
        const float4 bb = ((const float4*)b)[i4];
        float4 o;
        o.x = (v[r].x - mu) * inv * gg.x + bb.x;
        o.y = (v[r].y - mu) * inv * gg.y + bb.y;
        o.z = (v[r].z - mu) * inv * gg.z + bb.z;
        o.w = (v[r].w - mu) * inv * gg.w + bb.w;
        ((float4*)row)[i4] = o;
    }
}

extern "C" void kernel_launch(void* const* d_in, const int* in_sizes, int n_in,
                              void* d_out, int out_size, void* d_ws, size_t ws_size,
                              hipStream_t stream)
{
    (void)in_sizes; (void)n_in; (void)out_size; (void)ws_size;
    const float* x     = (const float*)d_in[0];
    const float* s0    = (const float*)d_in[1];
    const float* z0    = (const float*)d_in[2];
    const int*   start = (const int*)d_in[3];
    const float* Wk    = (const float*)d_in[5];
    const float* Wq    = (const float*)d_in[6];
    const float* Wv    = (const float*)d_in[7];
    const float* bv    = (const float*)d_in[8];
    const float* Wskip = (const float*)d_in[9];
    const float* bskip = (const float*)d_in[10];
    const float* W1    = (const float*)d_in[11];
    const float* b1    = (const float*)d_in[12];
    const float* W2    = (const float*)d_in[13];
    const float* b2    = (const float*)d_in[14];
    const float* W3    = (const float*)d_in[15];
    const float* b3    = (const float*)d_in[16];
    const float* ln_g  = (const float*)d_in[17];
    const float* ln_b  = (const float*)d_in[18];

    // ---- workspace carve (256B-aligned), total ~148 MB ----
    char* p = (char*)d_ws;
    auto alloc = [&](size_t bytes) -> void* {
        void* r = (void*)p; p += (bytes + 255) & ~(size_t)255; return r;
    };
    float* kbuf  = (float*)alloc((size_t)T_DIM * K_DIM * 4);
    float* qbuf  = (float*)alloc((size_t)T_DIM * K_DIM * 4);
    float* vbuf  = (float*)alloc((size_t)T_DIM * V_DIM * 4);
    float* chS   = (float*)alloc((size_t)CHUNKS * 4096 * 4);
    float* chZ   = (float*)alloc((size_t)CHUNKS * 64 * 4);
    float* caS   = (float*)alloc((size_t)CHUNKS * 4096 * 4);
    float* caZ   = (float*)alloc((size_t)CHUNKS * 64 * 4);
    int*   flags = (int*)  alloc((size_t)CHUNKS * 4);
    unsigned short* xb     = (unsigned short*)alloc((size_t)T_DIM * IN_DIM * 2);
    unsigned short* Wskipb = (unsigned short*)alloc((size_t)H_DIM * IN_DIM * 2);
    unsigned short* W1b    = (unsigned short*)alloc((size_t)H_DIM * V_DIM * 2);
    unsigned short* W2b    = (unsigned short*)alloc((size_t)H_DIM * H_DIM * 2);
    unsigned short* W3b    = (unsigned short*)alloc((size_t)H_DIM * H_DIM * 2);
    unsigned short* attb   = (unsigned short*)alloc((size_t)T_DIM * V_DIM * 2);
    unsigned short* h1b    = (unsigned short*)alloc((size_t)T_DIM * H_DIM * 2);
    unsigned short* h2b    = (unsigned short*)alloc((size_t)T_DIM * H_DIM * 2);

    float* hn  = (float*)d_out;                          // (T,H)
    float* s_o = hn  + (size_t)T_DIM * H_DIM;            // (T,K,V)
    float* z_o = s_o + (size_t)T_DIM * K_DIM * V_DIM;    // (T,1,K)

    // 0) prep: 3 projections + 5 bf16 conversions in ONE dispatch
    prep_kernel<<<2048, 256, 0, stream>>>(x, Wk, Wq, Wv, bv, kbuf, qbuf, vbuf,
                                          Wskip, W1, W2, W3, xb, Wskipb, W1b, W2b, W3b);

    // 1) segmented scan (3 ordinary dispatches; cooperative launch is NOT graph-capturable)
    scan_passA<<<CHUNKS, 256, 0, stream>>>(kbuf, vbuf, start, chS, chZ, flags);
    scan_passB<<<64, 64, 0, stream>>>(chS, chZ, flags, s0, z0, caS, caZ);
    scan_passC<<<CHUNKS, 256, 0, stream>>>(kbuf, vbuf, qbuf, start, caS, caZ, s_o, z_o, attb);

    // 2) MLP: all three GEMMs on the wave-pipelined 256^2 kernel
    gemm256p<<<dim3(16, 16), 512, 0, stream>>>(
        attb, W1b, K_DIM, nullptr, nullptr, 0, b1, nullptr, h1b, H_DIM, 2, 1);
    gemm256p<<<dim3(16, 16), 512, 0, stream>>>(
        h1b, W2b, H_DIM, nullptr, nullptr, 0, b2, nullptr, h2b, H_DIM, 2, 1);
    // GEMM3 fused with skip: hn = h2@W3^T + x@Wskip^T + b3 + bskip (fp32 out)
    gemm256p<<<dim3(16, 16), 512, 0, stream>>>(
        h2b, W3b, H_DIM, xb, Wskipb, IN_DIM, b3, bskip, hn, H_DIM, 0, 0);

    // 3) LayerNorm in place on d_out
    ln_kernel<<<T_DIM, 256, 0, stream>>>(hn, ln_g, ln_b);
}

// Round 12
// 637.955 us; speedup vs baseline: 1.0120x; 1.0120x over previous
//
#include <hip/hip_runtime.h>
#include <math.h>

// Problem constants (from reference): T=4096, IN=512, K=64, V=64, H=4096
#define T_DIM 4096
#define IN_DIM 512
#define K_DIM 64
#define V_DIM 64
#define H_DIM 4096
#define CHUNKS 256
#define CLEN 16   // T_DIM / CHUNKS

typedef __attribute__((ext_vector_type(8))) short short8;           // 8 bf16 = 4 VGPRs
typedef __attribute__((ext_vector_type(4))) float f32x4;

// ---------------- activations ----------------
__device__ __forceinline__ float phi_act(float v){
    return v > 0.f ? (v + 1.f) : (expm1f(v) + 1.f);
}
// mish(x) = x*tanh(softplus(x)) = x*(1 - 2/(u*(u+2)+2)), u=e^x  (exact identity).
// Branch-free; limits: x->+inf -> x (2/inf=0), x->-inf -> x*e^x -> 0.
// Validated on-hardware round 10 (absmax pass; cut GEMM2 VALUBusy 51%->17%).
__device__ __forceinline__ float mish_act(float v){
    const float u = __expf(v);
    const float w = u * (u + 2.f);
    return v * (1.f - 2.f / (w + 2.f));
}
// fp32 -> bf16 round-to-nearest-even (bit trick)
__device__ __forceinline__ unsigned short f2bf(float f){
    union { float f; unsigned int u; } x; x.f = f;
    unsigned int u = x.u + 0x7fffu + ((x.u >> 16) & 1u);
    return (unsigned short)(u >> 16);
}

// async 16B global->LDS (dest = wave-uniform base + lane*16; layout must be contiguous per lane)
__device__ __forceinline__ void async16(const unsigned short* g, unsigned short* l){
    __builtin_amdgcn_global_load_lds(
        (const __attribute__((address_space(1))) unsigned int*)g,
        (__attribute__((address_space(3))) unsigned int*)l,
        16, 0, 0);
}

// inline-asm ds_read_b128 with compile-time immediate offset. Opaque to the
// compiler's waitcnt insertion -> we control lgkmcnt/vmcnt entirely; offset:imm
// keeps address VALU at zero inside the K-loop.
__device__ __forceinline__ short8 dsr128o(unsigned addr, int off){
    short8 d;
    asm volatile("ds_read_b128 %0, %1 offset:%2" : "=v"(d) : "v"(addr), "i"(off));
    return d;
}

#define LGKM(n)  asm volatile("s_waitcnt lgkmcnt(" #n ")" ::: "memory")
#define VMCNT(n) asm volatile("s_waitcnt vmcnt(" #n ")" ::: "memory")
#define SB0()    __builtin_amdgcn_sched_barrier(0)

// ---------------- prep kernel: 3 fp32 projections + 5 bf16 conversions, ONE dispatch -----
// blocks 0..191: projection (which = bid>>6): {k=phi(x@Wk^T), q=phi(x@Wq^T), v=x@Wv^T+bv}
// blocks 192.. : grid-stride bf16 conversion over {x, Wskip, W1, W2, W3} (9502720 float4s)
#define CVT_X4   524288          // T*IN/4
#define CVT_WS   524288          // H*IN/4
#define CVT_W1   65536           // H*V/4
#define CVT_W2   4194304         // H*H/4
#define CVT_TOT  9502720
__global__ __launch_bounds__(256) void prep_kernel(
    const float* __restrict__ x,
    const float* __restrict__ Wk, const float* __restrict__ Wq, const float* __restrict__ Wv,
    const float* __restrict__ bv,
    float* __restrict__ kbuf, float* __restrict__ qbuf, float* __restrict__ vbuf,
    const float* __restrict__ Wskip, const float* __restrict__ W1,
    const float* __restrict__ W2, const float* __restrict__ W3,
    unsigned short* __restrict__ xb, unsigned short* __restrict__ Wskipb,
    unsigned short* __restrict__ W1b, unsigned short* __restrict__ W2b,
    unsigned short* __restrict__ W3b)
{
    __shared__ float As[16][68];
    __shared__ float Bs[16][68];
    const int bid = blockIdx.x;
    const int tid = threadIdx.x;

    if (bid < 192){
        // ---- projection path (uniform per block; __syncthreads is block-uniform) ----
        const int which = bid >> 6;
        const float* B0 = which == 0 ? Wk : which == 1 ? Wq : Wv;
        float* Y        = which == 0 ? kbuf : which == 1 ? qbuf : vbuf;
        const int actp  = which < 2;
        const int bm    = (bid & 63) * 64;
        const int lrow  = tid >> 2;
        const int lk4   = (tid & 3) * 4;
        const int tm    = (tid >> 4) * 4;
        const int tn    = (tid & 15) * 4;
        float acc[4][4] = {};
        const float* aptr = x  + (size_t)(bm + lrow) * IN_DIM + lk4;
        const float* bptr = B0 + (size_t)lrow * IN_DIM + lk4;
        for (int k0 = 0; k0 < IN_DIM; k0 += 16){
            const float4 av  = *(const float4*)(aptr + k0);
            const float4 bv4 = *(const float4*)(bptr + k0);
            __syncthreads();
            As[lk4+0][lrow]=av.x;  As[lk4+1][lrow]=av.y;  As[lk4+2][lrow]=av.z;  As[lk4+3][lrow]=av.w;
            Bs[lk4+0][lrow]=bv4.x; Bs[lk4+1][lrow]=bv4.y; Bs[lk4+2][lrow]=bv4.z; Bs[lk4+3][lrow]=bv4.w;
            __syncthreads();
            #pragma unroll
            for (int kk = 0; kk < 16; ++kk){
                const float4 a = *(const float4*)&As[kk][tm];
                const float4 b = *(const float4*)&Bs[kk][tn];
                acc[0][0] += a.x*b.x; acc[0][1] += a.x*b.y; acc[0][2] += a.x*b.z; acc[0][3] += a.x*b.w;
                acc[1][0] += a.y*b.x; acc[1][1] += a.y*b.y; acc[1][2] += a.y*b.z; acc[1][3] += a.y*b.w;
                acc[2][0] += a.z*b.x; acc[2][1] += a.z*b.y; acc[2][2] += a.z*b.z; acc[2][3] += a.z*b.w;
                acc[3][0] += a.w*b.x; acc[3][1] += a.w*b.y; acc[3][2] += a.w*b.z; acc[3][3] += a.w*b.w;
            }
        }
        float badd[4] = {0.f, 0.f, 0.f, 0.f};
        if (which == 2){
            badd[0] = bv[tn+0]; badd[1] = bv[tn+1]; badd[2] = bv[tn+2]; badd[3] = bv[tn+3];
        }
        #pragma unroll
        for (int i = 0; i < 4; ++i){
            float r0 = acc[i][0] + badd[0];
            float r1 = acc[i][1] + badd[1];
            float r2 = acc[i][2] + badd[2];
            float r3 = acc[i][3] + badd[3];
            if (actp){ r0 = phi_act(r0); r1 = phi_act(r1); r2 = phi_act(r2); r3 = phi_act(r3); }
            *(float4*)&Y[(size_t)(bm + tm + i) * 64 + tn] = make_float4(r0, r1, r2, r3);
        }
        return;
    }

    // ---- conversion path: grid-stride over 5 segments ----
    const int nb = gridDim.x - 192;
    for (int i = (bid - 192) * 256 + tid; i < CVT_TOT; i += nb * 256){
        const float* src; unsigned short* dst; int off;
        if      (i < CVT_X4)                          { src = x;     dst = xb;     off = i; }
        else if (i < CVT_X4 + CVT_WS)                 { src = Wskip; dst = Wskipb; off = i - CVT_X4; }
        else if (i < CVT_X4 + CVT_WS + CVT_W1)        { src = W1;    dst = W1b;    off = i - CVT_X4 - CVT_WS; }
        else if (i < CVT_X4 + CVT_WS + CVT_W1 + CVT_W2){ src = W2;   dst = W2b;    off = i - CVT_X4 - CVT_WS - CVT_W1; }
        else                                          { src = W3;    dst = W3b;    off = i - CVT_X4 - CVT_WS - CVT_W1 - CVT_W2; }
        float4 v = ((const float4*)src)[off];
        ushort4 o;
        o.x = f2bf(v.x); o.y = f2bf(v.y); o.z = f2bf(v.z); o.w = f2bf(v.w);
        ((ushort4*)dst)[off] = o;
    }
}

// ---------------- bf16 MFMA GEMM (128x128 tile, m97 structure) ----------------
// Used ONLY for GEMM1 (K=64 = single K-tile): 1024 blocks at ~4/CU give cross-block
// overlap that hides the serial stage->drain->compute->store chain (gemm256p's NT=1
// path has nothing to pipeline and runs 1 block/CU). Verified correct rounds 0-5.
__global__ __launch_bounds__(256) void gemm_mfma_bt(
    const unsigned short* __restrict__ A0, const unsigned short* __restrict__ B0, int K0,
    const float* __restrict__ bias0,
    void* __restrict__ Y, int N, int act, int out_bf16)
{
    constexpr int BK = 64;
    __shared__ unsigned short As[128 * BK];
    __shared__ unsigned short Bs[128 * BK];
    const int tid  = threadIdx.x;
    const int lane = tid & 63;
    const int wm   = (tid >> 6 & 1) * 64;     // wave m-offset in tile
    const int wn   = (tid >> 7) * 64;         // wave n-offset in tile
    const int bm   = blockIdx.x * 128;
    const int bn   = blockIdx.y * 128;
    const int l15  = lane & 15;
    const int quad = lane >> 4;

    f32x4 acc[4][4] = {};

    for (int k0 = 0; k0 < K0; k0 += BK){
        __syncthreads();  // previous tile's ds_reads must drain before restage
        #pragma unroll
        for (int it = 0; it < 4; ++it){   // 1024 chunks of 16B per matrix, 4 per thread
            const int c  = it * 256 + tid;        // LDS chunk index (byte off = c*16)
            const int r  = c >> 3;                // row 0..127
            const int kc = (c & 7) ^ (r & 7);     // swizzled global k-chunk
            async16(A0 + (size_t)(bm + r) * K0 + k0 + kc * 8, &As[c * 8]);
        }
        #pragma unroll
        for (int it = 0; it < 4; ++it){
            const int c  = it * 256 + tid;
            const int r  = c >> 3;
            const int kc = (c & 7) ^ (r & 7);
            async16(B0 + (size_t)(bn + r) * K0 + k0 + kc * 8, &Bs[c * 8]);
        }
        __syncthreads();  // s_waitcnt vmcnt(0) before s_barrier -> staging complete
        #pragma unroll
        for (int ks = 0; ks < 2; ++ks){
            short8 af[4], bf[4];
            #pragma unroll
            for (int mi = 0; mi < 4; ++mi){
                const int row = wm + mi * 16 + l15;
                const int kq  = ks * 4 + quad;            // k-chunk 0..7
                af[mi] = *(const short8*)&As[(row * 8 + (kq ^ (row & 7))) * 8];
            }
            #pragma unroll
            for (int ni = 0; ni < 4; ++ni){
                const int row = wn + ni * 16 + l15;
                const int kq  = ks * 4 + quad;
                bf[ni] = *(const short8*)&Bs[(row * 8 + (kq ^ (row & 7))) * 8];
            }
            #pragma unroll
            for (int mi = 0; mi < 4; ++mi)
                #pragma unroll
                for (int ni = 0; ni < 4; ++ni)
                    acc[mi][ni] = __builtin_amdgcn_mfma_f32_16x16x32_bf16(
                        af[mi], bf[ni], acc[mi][ni], 0, 0, 0);
        }
    }

    // epilogue: C/D mapping col=lane&15, row=quad*4+reg
    #pragma unroll
    for (int ni = 0; ni < 4; ++ni){
        const int col = bn + wn + ni * 16 + l15;
        const float bb = bias0 ? bias0[col] : 0.f;
        #pragma unroll
        for (int mi = 0; mi < 4; ++mi){
            #pragma unroll
            for (int r = 0; r < 4; ++r){
                const int row = bm + wm + mi * 16 + quad * 4 + r;
                float v = acc[mi][ni][r] + bb;
                if (act == 2) v = mish_act(v);
                if (out_bf16) ((unsigned short*)Y)[(size_t)row * N + col] = f2bf(v);
                else          ((float*)Y)[(size_t)row * N + col] = v;
            }
        }
    }
}

// ---------------- 256x256 wave-pipelined bf16 MFMA GEMM (round-11 verified form) ----------------
// BM=BN=256, BK=64, double-buffered LDS (128 KiB, 1 block/CU). 512 threads = 8 waves
// (2M x 4N); per-wave output 128x64 = acc f32x4[8][4] (AGPR).
// ONE barrier per K-tile; per-wave counted lgkmcnt LADDER (DS completes in-order/wave);
// the 8 staging loads of tile t+1 are SPREAD 4-2-2 across the MFMA clusters (round-11
// measured: 161.6 -> 145-147 us, MfmaUtil 41 -> 45-46%). Race-safety: staging targets
// buf (t+1)&1 (never read during tile t); boundary VMCNT(0) + s_barrier publishes;
// lgkm ladder counts only DS ops (global_load_lds is vmcnt-only). Last staged pair
// ages ~2 clusters (~3000 cyc >> 900-cyc HBM latency). Swizzle measured 0-conflict.
// Direct-store epilogue (LDS-staged variant measured +18us/GEMM -- rejected).
// Two K-segments accumulate into the same acc (fuses skip-GEMM into GEMM3).
__global__ __launch_bounds__(512, 2) void gemm256p(
    const unsigned short* __restrict__ A0, const unsigned short* __restrict__ B0, int K0,
    const unsigned short* __restrict__ A1, const unsigned short* __restrict__ B1, int K1,
    const float* __restrict__ bias0, const float* __restrict__ bias1,
    void* __restrict__ Y, int N, int act, int out_bf16)
{
    __shared__ unsigned short As[2][16384];   // 2 x 32 KiB
    __shared__ unsigned short Bs[2][16384];   // 2 x 32 KiB
    const int tid  = threadIdx.x;
    const int lane = tid & 63;
    const int w    = tid >> 6;          // wave 0..7
    const int wr   = w >> 2;            // 0..1  (M half)
    const int wc   = w & 3;             // 0..3  (N quarter)
    const int l15  = lane & 15;
    const int quad = lane >> 4;

    // Bijective XCD-aware swizzle for the 16x16 grid: XCD x owns a 4(M) x 8(N) patch.
    int bx = blockIdx.x, by = blockIdx.y;
    if (gridDim.x == 16 && gridDim.y == 16){
        const int id  = by * 16 + bx;       // dispatch-linear (blockIdx.x fastest)
        const int xcd = id & 7;             // default round-robin XCD assignment
        const int loc = id >> 3;            // 0..31 within XCD
        bx = (xcd & 3) * 4 + (loc & 3);
        by = (xcd >> 2) * 8 + (loc >> 2);
    }
    const int bm = bx * 256;
    const int bn = by * 256;

    // staging geometry: thread owns chunk g*512+tid of each 2048-chunk tile (16 B each);
    // row = g*64 + (tid>>3), swizzled k-chunk kc = (tid&7) ^ (row&7).
    const int r0 = tid >> 3;
    const int kc = (tid & 7) ^ (r0 & 7);

    // loop-invariant LDS read bases (buffer 0); frag mi at +mi*2048 B, buffer 1 at +32768 B.
    const unsigned asB = (unsigned)(size_t)&As[0][0];
    const unsigned bsB = (unsigned)(size_t)&Bs[0][0];
    const unsigned bA0 = asB + (unsigned)(((wr * 128 + l15) * 8 + ((0 + quad) ^ (l15 & 7))) * 16);
    const unsigned bA1 = asB + (unsigned)(((wr * 128 + l15) * 8 + ((4 + quad) ^ (l15 & 7))) * 16);
    const unsigned bB0 = bsB + (unsigned)(((wc * 64  + l15) * 8 + ((0 + quad) ^ (l15 & 7))) * 16);
    const unsigned bB1 = bsB + (unsigned)(((wc * 64  + l15) * 8 + ((4 + quad) ^ (l15 & 7))) * 16);

    f32x4 acc[8][4] = {};

    for (int seg = 0; seg < 2; ++seg){
        const unsigned short* A = seg ? A1 : A0;
        const unsigned short* B = seg ? B1 : B0;
        const int Kd = seg ? K1 : K0;
        if (Kd <= 0 || A == nullptr) continue;
        const int NT = Kd / 64;
        const size_t gstride = (size_t)64 * Kd;
        const unsigned short* pA = A + (size_t)bm * Kd + (size_t)r0 * Kd + kc * 8;
        const unsigned short* pB = B + (size_t)bn * Kd + (size_t)r0 * Kd + kc * 8;

        // ---- prologue: stage tile 0 into buf0, drain, publish ----
        #pragma unroll
        for (int g = 0; g < 4; ++g) async16(pA + g * gstride, &As[0][(g * 512 + tid) * 8]);
        #pragma unroll
        for (int g = 0; g < 4; ++g) async16(pB + g * gstride, &Bs[0][(g * 512 + tid) * 8]);
        VMCNT(0);
        __builtin_amdgcn_s_barrier();

        for (int t = 0; t < NT; ++t){
            const unsigned bo = (unsigned)(t & 1) * 32768u;
            const unsigned aA0 = bA0 + bo, aA1 = bA1 + bo, aB0 = bB0 + bo, aB1 = bB1 + bo;
            const bool st = (t + 1 < NT);
            const int  bi = (t + 1) & 1;
            const int  kn = (t + 1) * 64;
            short8 fa0[4], fa1[4], fb0[4], fb1[4];

            // issue fb0 (ops 1-4), fa0 (5-8); stage A g0,g1 + B g0,g1; fa1 (9-12)
            #pragma unroll
            for (int ni = 0; ni < 4; ++ni) fb0[ni] = dsr128o(aB0, ni * 2048);
            #pragma unroll
            for (int mi = 0; mi < 4; ++mi) fa0[mi] = dsr128o(aA0, mi * 2048);
            if (st){
                async16(pA + 0 * gstride + kn, &As[bi][(0 * 512 + tid) * 8]);
                async16(pA + 1 * gstride + kn, &As[bi][(1 * 512 + tid) * 8]);
                async16(pB + 0 * gstride + kn, &Bs[bi][(0 * 512 + tid) * 8]);
                async16(pB + 1 * gstride + kn, &Bs[bi][(1 * 512 + tid) * 8]);
            }
            #pragma unroll
            for (int mi = 0; mi < 4; ++mi) fa1[mi] = dsr128o(aA0, (4 + mi) * 2048);

            // cluster 0: acc[0:4] x fb0 (needs ops 1-8), laddered per mi
            __builtin_amdgcn_s_setprio(1);
            LGKM(7); SB0();
            #pragma unroll
            for (int ni = 0; ni < 4; ++ni)
                acc[0][ni] = __builtin_amdgcn_mfma_f32_16x16x32_bf16(fa0[0], fb0[ni], acc[0][ni], 0, 0, 0);
            LGKM(6); SB0();
            #pragma unroll
            for (int ni = 0; ni < 4; ++ni)
                acc[1][ni] = __builtin_amdgcn_mfma_f32_16x16x32_bf16(fa0[1], fb0[ni], acc[1][ni], 0, 0, 0);
            LGKM(5); SB0();
            #pragma unroll
            for (int ni = 0; ni < 4; ++ni)
                acc[2][ni] = __builtin_amdgcn_mfma_f32_16x16x32_bf16(fa0[2], fb0[ni], acc[2][ni], 0, 0, 0);
            LGKM(4); SB0();
            #pragma unroll
            for (int ni = 0; ni < 4; ++ni)
                acc[3][ni] = __builtin_amdgcn_mfma_f32_16x16x32_bf16(fa0[3], fb0[ni], acc[3][ni], 0, 0, 0);
            __builtin_amdgcn_s_setprio(0);

            // stage A g2 + B g2 (spread); then issue fb1 (13-16), fa0' (17-20)
            if (st){
                async16(pA + 2 * gstride + kn, &As[bi][(2 * 512 + tid) * 8]);
                async16(pB + 2 * gstride + kn, &Bs[bi][(2 * 512 + tid) * 8]);
            }
            #pragma unroll
            for (int ni = 0; ni < 4; ++ni) fb1[ni] = dsr128o(aB1, ni * 2048);
            #pragma unroll
            for (int mi = 0; mi < 4; ++mi) fa0[mi] = dsr128o(aA1, mi * 2048);

            // cluster 1: acc[4:8] x fb0 (needs fa1 = ops 9-12), laddered
            __builtin_amdgcn_s_setprio(1);
            LGKM(11); SB0();
            #pragma unroll
            for (int ni = 0; ni < 4; ++ni)
                acc[4][ni] = __builtin_amdgcn_mfma_f32_16x16x32_bf16(fa1[0], fb0[ni], acc[4][ni], 0, 0, 0);
            LGKM(10); SB0();
            #pragma unroll
            for (int ni = 0; ni < 4; ++ni)
                acc[5][ni] = __builtin_amdgcn_mfma_f32_16x16x32_bf16(fa1[1], fb0[ni], acc[5][ni], 0, 0, 0);
            LGKM(9); SB0();
            #pragma unroll
            for (int ni = 0; ni < 4; ++ni)
                acc[6][ni] = __builtin_amdgcn_mfma_f32_16x16x32_bf16(fa1[2], fb0[ni], acc[6][ni], 0, 0, 0);
            LGKM(8); SB0();
            #pragma unroll
            for (int ni = 0; ni < 4; ++ni)
                acc[7][ni] = __builtin_amdgcn_mfma_f32_16x16x32_bf16(fa1[3], fb0[ni], acc[7][ni], 0, 0, 0);
            __builtin_amdgcn_s_setprio(0);

            // stage A g3 + B g3 (spread, last pair; ages clusters 2+3); issue fa1' (21-24)
            if (st){
                async16(pA + 3 * gstride + kn, &As[bi][(3 * 512 + tid) * 8]);
                async16(pB + 3 * gstride + kn, &Bs[bi][(3 * 512 + tid) * 8]);
            }
            #pragma unroll
            for (int mi = 0; mi < 4; ++mi) fa1[mi] = dsr128o(aA1, (4 + mi) * 2048);

            // cluster 2: acc[0:4] x fb1 (needs ops 13-20), laddered
            __builtin_amdgcn_s_setprio(1);
            LGKM(7); SB0();
            #pragma unroll
            for (int ni = 0; ni < 4; ++ni)
                acc[0][ni] = __builtin_amdgcn_mfma_f32_16x16x32_bf16(fa0[0], fb1[ni], acc[0][ni], 0, 0, 0);
            LGKM(6); SB0();
            #pragma unroll
            for (int ni = 0; ni < 4; ++ni)
                acc[1][ni] = __builtin_amdgcn_mfma_f32_16x16x32_bf16(fa0[1], fb1[ni], acc[1][ni], 0, 0, 0);
            LGKM(5); SB0();
            #pragma unroll
            for (int ni = 0; ni < 4; ++ni)
                acc[2][ni] = __builtin_amdgcn_mfma_f32_16x16x32_bf16(fa0[2], fb1[ni], acc[2][ni], 0, 0, 0);
            LGKM(4); SB0();
            #pragma unroll
            for (int ni = 0; ni < 4; ++ni)
                acc[3][ni] = __builtin_amdgcn_mfma_f32_16x16x32_bf16(fa0[3], fb1[ni], acc[3][ni], 0, 0, 0);

            // cluster 3: acc[4:8] x fb1 (needs ops 21-24), laddered
            LGKM(3); SB0();
            #pragma unroll
            for (int ni = 0; ni < 4; ++ni)
                acc[4][ni] = __builtin_amdgcn_mfma_f32_16x16x32_bf16(fa1[0], fb1[ni], acc[4][ni], 0, 0, 0);
            LGKM(2); SB0();
            #pragma unroll
            for (int ni = 0; ni < 4; ++ni)
                acc[5][ni] = __builtin_amdgcn_mfma_f32_16x16x32_bf16(fa1[1], fb1[ni], acc[5][ni], 0, 0, 0);
            LGKM(1); SB0();
            #pragma unroll
            for (int ni = 0; ni < 4; ++ni)
                acc[6][ni] = __builtin_amdgcn_mfma_f32_16x16x32_bf16(fa1[2], fb1[ni], acc[6][ni], 0, 0, 0);
            LGKM(0); SB0();
            #pragma unroll
            for (int ni = 0; ni < 4; ++ni)
                acc[7][ni] = __builtin_amdgcn_mfma_f32_16x16x32_bf16(fa1[3], fb1[ni], acc[7][ni], 0, 0, 0);
            __builtin_amdgcn_s_setprio(0);

            // tile boundary: own tile-t+1 loads drained, then publish.
            if (st){
                VMCNT(0);
                __builtin_amdgcn_s_barrier();
            }
        }
        // inter-segment: next prologue's VMCNT(0)+barrier is the rendezvous; buffer
        // written next (buf0) had its reads complete before the last boundary barrier.
    }

    // epilogue (direct stores): C/D mapping col=lane&15, row=quad*4+reg
    #pragma unroll
    for (int ni = 0; ni < 4; ++ni){
        const int col = bn + wc * 64 + ni * 16 + l15;
        float bb = 0.f;
        if (bias0) bb += bias0[col];
        if (bias1) bb += bias1[col];
        #pragma unroll
        for (int mi = 0; mi < 8; ++mi){
            #pragma unroll
            for (int r = 0; r < 4; ++r){
                const int row = bm + wr * 128 + mi * 16 + quad * 4 + r;
                float v = acc[mi][ni][r] + bb;
                if (act == 2) v = mish_act(v);
                if (out_bf16) ((unsigned short*)Y)[(size_t)row * N + col] = f2bf(v);
                else          ((float*)Y)[(size_t)row * N + col] = v;
            }
        }
    }
}

// ---------------- segmented scan, pass A (one-shot LDS chunk load, barrier-free loop) ----
__global__ __launch_bounds__(256) void scan_passA(
    const float* __restrict__ kbuf, const float* __restrict__ vbuf,
    const int* __restrict__ start,
    float* __restrict__ chunkS, float* __restrict__ chunkZ, int* __restrict__ chunkFlag)
{
    const int c   = blockIdx.x;
    const int tid = threadIdx.x;
    const int j   = tid >> 2;
    const int i0  = (tid & 3) * 16;
    __shared__ float k_lds[CLEN][64], v_lds[CLEN][64];
    __shared__ int   st_lds[CLEN];
    // one-shot chunk load: 16 rows x 64 floats = 256 float4 (coalesced)
    ((float4*)&k_lds[0][0])[tid] = ((const float4*)(kbuf + (size_t)c * CLEN * K_DIM))[tid];
    ((float4*)&v_lds[0][0])[tid] = ((const float4*)(vbuf + (size_t)c * CLEN * V_DIM))[tid];
    if (tid < CLEN) st_lds[tid] = start[c * CLEN + tid];
    __syncthreads();

    float s_loc[16];
    #pragma unroll
    for (int e = 0; e < 16; ++e) s_loc[e] = 0.f;
    float z_loc = 0.f;
    int flag = 0;
    for (int tt = 0; tt < CLEN; ++tt){
        if (st_lds[tt]){
            #pragma unroll
            for (int e = 0; e < 16; ++e) s_loc[e] = 0.f;
            z_loc = 0.f;
            flag = 1;
        }
        const float vj = v_lds[tt][j];
        #pragma unroll
        for (int e = 0; e < 16; ++e) s_loc[e] += k_lds[tt][i0 + e] * vj;
        if (tid < 64) z_loc += k_lds[tt][tid];
    }
    #pragma unroll
    for (int e = 0; e < 16; ++e) chunkS[(size_t)c*4096 + (i0 + e)*64 + j] = s_loc[e];
    if (tid < 64) chunkZ[c*64 + tid] = z_loc;
    if (tid == 0) chunkFlag[c] = flag;
}

// ---------------- pass B: exclusive cross-chunk combine (64 blocks x 64 thr) ----------------
__global__ __launch_bounds__(64) void scan_passB(
    const float* __restrict__ chunkS, const float* __restrict__ chunkZ, const int* __restrict__ chunkFlag,
    const float* __restrict__ s0, const float* __restrict__ z0,
    float* __restrict__ carryS, float* __restrict__ carryZ)
{
    const int ij = blockIdx.x * 64 + threadIdx.x;
    float e = s0[ij];
    for (int c = 0; c < CHUNKS; ++c){
        carryS[(size_t)c*4096 + ij] = e;
        const int f   = chunkFlag[c];
        const float s = chunkS[(size_t)c*4096 + ij];
        e = f ? s : (e + s);
    }
    if (ij < 64){
        float ez = z0[ij];
        for (int c = 0; c < CHUNKS; ++c){
            carryZ[c*64 + ij] = ez;
            const int f   = chunkFlag[c];
            const float z = chunkZ[c*64 + ij];
            ez = f ? z : (ez + z);
        }
    }
}

// ---------------- pass C: replay with carry (one-shot LDS chunk load); emit s,z,att ----
__global__ __launch_bounds__(256) void scan_passC(
    const float* __restrict__ kbuf, const float* __restrict__ vbuf, const float* __restrict__ qbuf,
    const int* __restrict__ start,
    const float* __restrict__ carryS, const float* __restrict__ carryZ,
    float* __restrict__ s_out, float* __restrict__ z_out, unsigned short* __restrict__ attout)
{
    const int c   = blockIdx.x;
    const int tid = threadIdx.x;
    const int j   = tid >> 2;
    const int g   = tid & 3;
    const int i0  = g * 16;
    __shared__ float k_lds[CLEN][64], v_lds[CLEN][64], q_lds[CLEN][64];
    __shared__ int   st_lds[CLEN];
    __shared__ float numer_lds[64];
    __shared__ float stage[4096];
    // one-shot chunk load
    ((float4*)&k_lds[0][0])[tid] = ((const float4*)(kbuf + (size_t)c * CLEN * K_DIM))[tid];
    ((float4*)&v_lds[0][0])[tid] = ((const float4*)(vbuf + (size_t)c * CLEN * V_DIM))[tid];
    ((float4*)&q_lds[0][0])[tid] = ((const float4*)(qbuf + (size_t)c * CLEN * K_DIM))[tid];
    if (tid < CLEN) st_lds[tid] = start[c * CLEN + tid];

    float s_loc[16];
    #pragma unroll
    for (int e = 0; e < 16; ++e) s_loc[e] = carryS[(size_t)c*4096 + (i0 + e)*64 + j];
    float z_loc = (tid < 64) ? carryZ[c*64 + tid] : 0.f;
    __syncthreads();

    const int t0 = c * CLEN;
    for (int tt = 0; tt < CLEN; ++tt){
        const int t  = t0 + tt;
        const int st = st_lds[tt];
        if (st){
            #pragma unroll
            for (int e = 0; e < 16; ++e) s_loc[e] = 0.f;
        }
        const float vj = v_lds[tt][j];
        float np = 0.f;
        #pragma unroll
        for (int e = 0; e < 16; ++e){
            s_loc[e] += k_lds[tt][i0 + e] * vj;
            np += s_loc[e] * q_lds[tt][i0 + e];
        }
        np += __shfl_down(np, 1, 64);
        np += __shfl_down(np, 2, 64);
        if (g == 0) numer_lds[j] = np;
        float denom = 1.f;
        if (tid < 64){
            z_loc = (st ? 0.f : z_loc) + k_lds[tt][tid];
            z_out[(size_t)t*K_DIM + tid] = z_loc;
            float zs = z_loc;
            float qs = q_lds[tt][tid];
            #pragma unroll
            for (int o = 32; o > 0; o >>= 1){
                zs += __shfl_down(zs, o, 64);
                qs += __shfl_down(qs, o, 64);
            }
            zs = __shfl(zs, 0, 64);
            qs = __shfl(qs, 0, 64);
            denom = fmaxf(zs * qs, 1e-6f);
        }
        #pragma unroll
        for (int e = 0; e < 16; ++e) stage[(i0 + e)*64 + j] = s_loc[e];
        __syncthreads();
        float4* so = (float4*)(s_out + (size_t)t*4096);
        const float4* stv = (const float4*)stage;
        #pragma unroll
        for (int r = 0; r < 4; ++r) so[tid + 256*r] = stv[tid + 256*r];
        if (tid < 64) attout[(size_t)t*V_DIM + tid] = f2bf(numer_lds[tid] / denom);
        __syncthreads();
    }
}

// ---------------- LayerNorm over H=4096, in place ----------------
__global__ __launch_bounds__(256) void ln_kernel(
    float* __restrict__ h, const float* __restrict__ g, const float* __restrict__ b)
{
    __shared__ float sm[4];
    const int t   = blockIdx.x;
    const int tid = threadIdx.x;
    float* row = h + (size_t)t * H_DIM;
    float4 v[4];
    float s = 0.f;
    #pragma unroll
    for (int r = 0; r < 4; ++r){
        v[r] = ((const float4*)row)[tid + 256*r];
        s += v[r].x + v[r].y + v[r].z + v[r].w;
    }
    #pragma unroll
    for (int o = 32; o > 0; o >>= 1) s += __shfl_down(s, o, 64);
    if ((tid & 63) == 0) sm[tid >> 6] = s;
    __syncthreads();
    const float mu = (sm[0] + sm[1] + sm[2] + sm[3]) * (1.f / H_DIM);
    __syncthreads();
    float sq = 0.f;
    #pragma unroll
    for (int r = 0; r < 4; ++r){
        float dx = v[r].x - mu, dy = v[r].y - mu, dz = v[r].z - mu, dw = v[r].w - mu;
        sq += dx*dx + dy*dy + dz*dz + dw*dw;
    }
    #pragma unroll
    for (int o = 32; o > 0; o >>= 1) sq += __shfl_down(sq, o, 64);
    if ((tid & 63) == 0) sm[tid >> 6] = sq;
    __syncthreads();
    const float var = (sm[0] + sm[1] + sm[2] + sm[3]) * (1.f / H_DIM);
    const float inv = rsqrtf(var + 1e-5f);
    #pragma unroll
    for (int r = 0; r < 4; ++r){
        const int i4 = tid + 256*r;
        const float4 gg = ((const float4*)g)[i4];
        const float4 bb = ((const float4*)b)[i4];
        float4 o;
        o.x = (v[r].x - mu) * inv * gg.x + bb.x;
        o.y = (v[r].y - mu) * inv * gg.y + bb.y;
        o.z = (v[r].z - mu) * inv * gg.z + bb.z;
        o.w = (v[r].w - mu) * inv * gg.w + bb.w;
        ((float4*)row)[i4] = o;
    }
}

extern "C" void kernel_launch(void* const* d_in, const int* in_sizes, int n_in,
                              void* d_out, int out_size, void* d_ws, size_t ws_size,
                              hipStream_t stream)
{
    (void)in_sizes; (void)n_in; (void)out_size; (void)ws_size;
    const float* x     = (const float*)d_in[0];
    const float* s0    = (const float*)d_in[1];
    const float* z0    = (const float*)d_in[2];
    const int*   start = (const int*)d_in[3];
    const float* Wk    = (const float*)d_in[5];
    const float* Wq    = (const float*)d_in[6];
    const float* Wv    = (const float*)d_in[7];
    const float* bv    = (const float*)d_in[8];
    const float* Wskip = (const float*)d_in[9];
    const float* bskip = (const float*)d_in[10];
    const float* W1    = (const float*)d_in[11];
    const float* b1    = (const float*)d_in[12];
    const float* W2    = (const float*)d_in[13];
    const float* b2    = (const float*)d_in[14];
    const float* W3    = (const float*)d_in[15];
    const float* b3    = (const float*)d_in[16];
    const float* ln_g  = (const float*)d_in[17];
    const float* ln_b  = (const float*)d_in[18];

    // ---- workspace carve (256B-aligned), total ~148 MB ----
    char* p = (char*)d_ws;
    auto alloc = [&](size_t bytes) -> void* {
        void* r = (void*)p; p += (bytes + 255) & ~(size_t)255; return r;
    };
    float* kbuf  = (float*)alloc((size_t)T_DIM * K_DIM * 4);
    float* qbuf  = (float*)alloc((size_t)T_DIM * K_DIM * 4);
    float* vbuf  = (float*)alloc((size_t)T_DIM * V_DIM * 4);
    float* chS   = (float*)alloc((size_t)CHUNKS * 4096 * 4);
    float* chZ   = (float*)alloc((size_t)CHUNKS * 64 * 4);
    float* caS   = (float*)alloc((size_t)CHUNKS * 4096 * 4);
    float* caZ   = (float*)alloc((size_t)CHUNKS * 64 * 4);
    int*   flags = (int*)  alloc((size_t)CHUNKS * 4);
    unsigned short* xb     = (unsigned short*)alloc((size_t)T_DIM * IN_DIM * 2);
    unsigned short* Wskipb = (unsigned short*)alloc((size_t)H_DIM * IN_DIM * 2);
    unsigned short* W1b    = (unsigned short*)alloc((size_t)H_DIM * V_DIM * 2);
    unsigned short* W2b    = (unsigned short*)alloc((size_t)H_DIM * H_DIM * 2);
    unsigned short* W3b    = (unsigned short*)alloc((size_t)H_DIM * H_DIM * 2);
    unsigned short* attb   = (unsigned short*)alloc((size_t)T_DIM * V_DIM * 2);
    unsigned short* h1b    = (unsigned short*)alloc((size_t)T_DIM * H_DIM * 2);
    unsigned short* h2b    = (unsigned short*)alloc((size_t)T_DIM * H_DIM * 2);

    float* hn  = (float*)d_out;                          // (T,H)
    float* s_o = hn  + (size_t)T_DIM * H_DIM;            // (T,K,V)
    float* z_o = s_o + (size_t)T_DIM * K_DIM * V_DIM;    // (T,1,K)

    // 0) prep: 3 projections + 5 bf16 conversions in ONE dispatch
    prep_kernel<<<2048, 256, 0, stream>>>(x, Wk, Wq, Wv, bv, kbuf, qbuf, vbuf,
                                          Wskip, W1, W2, W3, xb, Wskipb, W1b, W2b, W3b);

    // 1) segmented scan (3 ordinary dispatches; cooperative launch is NOT graph-capturable)
    scan_passA<<<CHUNKS, 256, 0, stream>>>(kbuf, vbuf, start, chS, chZ, flags);
    scan_passB<<<64, 64, 0, stream>>>(chS, chZ, flags, s0, z0, caS, caZ);
    scan_passC<<<CHUNKS, 256, 0, stream>>>(kbuf, vbuf, qbuf, start, caS, caZ, s_o, z_o, attb);

    // 2) MLP: GEMM1 (K=64, single tile) on the 128^2 many-blocks kernel; big GEMMs on
    //    the wave-pipelined 256^2 kernel.
    gemm_mfma_bt<<<dim3(T_DIM/128, H_DIM/128), 256, 0, stream>>>(
        attb, W1b, K_DIM, b1, h1b, H_DIM, 2, 1);
    gemm256p<<<dim3(16, 16), 512, 0, stream>>>(
        h1b, W2b, H_DIM, nullptr, nullptr, 0, b2, nullptr, h2b, H_DIM, 2, 1);
    // GEMM3 fused with skip: hn = h2@W3^T + x@Wskip^T + b3 + bskip (fp32 out)
    gemm256p<<<dim3(16, 16), 512, 0, stream>>>(
        h2b, W3b, H_DIM, xb, Wskipb, IN_DIM, b3, bskip, hn, H_DIM, 0, 0);

    // 3) LayerNorm in place on d_out
    ln_kernel<<<T_DIM, 256, 0, stream>>>(hn, ln_g, ln_b);
}